// Round 3
// baseline (41.963 us; speedup 1.0000x reference)
//
#include <hip/hip_runtime.h>
#include <hip/hip_bf16.h>

// CoarseGrain: avg-pool SCALE=4 over last dim of (128, 4, 65536) fp32.
// out[n,c,l] = mean(x[n,c,4l:4l+4]).  Memory-bound streaming kernel.
//
// Each thread computes 4 outputs (one 16B store) from 4×16B loads,
// fully coalesced. Exact grid (no grid-stride loop) + non-temporal
// hints (zero-reuse streaming data). Use clang ext_vector_type, not
// HIP float4, so __builtin_nontemporal_* accepts the pointer.

typedef float v4f __attribute__((ext_vector_type(4)));

__global__ __launch_bounds__(256) void CoarseGrain_26474178413228_kernel(
    const float* __restrict__ x, float* __restrict__ out) {
    const v4f* __restrict__ in4 = reinterpret_cast<const v4f*>(x);
    v4f* __restrict__ out4 = reinterpret_cast<v4f*>(out);

    int i = blockIdx.x * blockDim.x + threadIdx.x;

    v4f a = __builtin_nontemporal_load(&in4[4 * i + 0]);
    v4f b = __builtin_nontemporal_load(&in4[4 * i + 1]);
    v4f c = __builtin_nontemporal_load(&in4[4 * i + 2]);
    v4f d = __builtin_nontemporal_load(&in4[4 * i + 3]);
    v4f r;
    r.x = (a.x + a.y + a.z + a.w) * 0.25f;
    r.y = (b.x + b.y + b.z + b.w) * 0.25f;
    r.z = (c.x + c.y + c.z + c.w) * 0.25f;
    r.w = (d.x + d.y + d.z + d.w) * 0.25f;
    __builtin_nontemporal_store(r, &out4[i]);
}

extern "C" void kernel_launch(void* const* d_in, const int* in_sizes, int n_in,
                              void* d_out, int out_size, void* d_ws, size_t ws_size,
                              hipStream_t stream) {
    const float* x = (const float*)d_in[0];
    float* out = (float*)d_out;

    // out_size = 128*4*16384 = 8,388,608; n_out4 = 2,097,152 = 8192 * 256
    int n_out4 = out_size / 4;
    const int block = 256;
    int grid = n_out4 / block;  // exact: out_size is a multiple of 1024

    CoarseGrain_26474178413228_kernel<<<grid, block, 0, stream>>>(x, out);
}

// Round 4
// 28.935 us; speedup vs baseline: 1.4502x; 1.4502x over previous
//
#include <hip/hip_runtime.h>
#include <hip/hip_bf16.h>

// CoarseGrain: avg-pool SCALE=4 over last dim of (128, 4, 65536) fp32.
// out[n,c,l] = mean(x[n,c,4l:4l+4]).  Memory-bound streaming kernel.
//
// Wave-dense variant: each thread issues 4 float4 loads at BLOCK stride
// (lane l of load k reads blk_base + k*256 + l), so every load
// instruction is fully contiguous across the wave (1 KB dense/wave).
// Each float4 collapses to one output scalar; 4 wave-dense scalar
// stores. No non-temporal hints (R3 showed nt regresses 42%).

typedef float v4f __attribute__((ext_vector_type(4)));

__global__ __launch_bounds__(256) void CoarseGrain_26474178413228_kernel(
    const float* __restrict__ x, float* __restrict__ out) {
    const v4f* __restrict__ in4 = reinterpret_cast<const v4f*>(x);

    // Each block handles 1024 consecutive float4 inputs (16 KB) ->
    // 1024 consecutive float outputs (4 KB).
    int base = blockIdx.x * 1024 + threadIdx.x;  // in float4 / float units

    v4f a = in4[base + 0 * 256];
    v4f b = in4[base + 1 * 256];
    v4f c = in4[base + 2 * 256];
    v4f d = in4[base + 3 * 256];

    out[base + 0 * 256] = (a.x + a.y + a.z + a.w) * 0.25f;
    out[base + 1 * 256] = (b.x + b.y + b.z + b.w) * 0.25f;
    out[base + 2 * 256] = (c.x + c.y + c.z + c.w) * 0.25f;
    out[base + 3 * 256] = (d.x + d.y + d.z + d.w) * 0.25f;
}

extern "C" void kernel_launch(void* const* d_in, const int* in_sizes, int n_in,
                              void* d_out, int out_size, void* d_ws, size_t ws_size,
                              hipStream_t stream) {
    const float* x = (const float*)d_in[0];
    float* out = (float*)d_out;

    // out_size = 8,388,608 floats; each block produces 1024 outputs.
    int grid = out_size / 1024;  // = 8192, exact

    CoarseGrain_26474178413228_kernel<<<grid, 256, 0, stream>>>(x, out);
}